// Round 4
// baseline (88.202 us; speedup 1.0000x reference)
//
#include <hip/hip_runtime.h>

// Pointer-generator final distribution, fused, LDS-scatter version.
// out[b,t,v] = p*vocab[b,t,v] (v<V) + scatter_add((1-p)*attn at ids), pad=0.
//
// One block per (b,t) row. Row processed in LDS chunks: zero LDS -> scatter
// (1-p)*attn for ids falling in this chunk (LDS atomics; duplicates
// accumulate, matching tf.scatter_nd) -> stream out = p*vocab + lds with
// nontemporal load/store (pure streaming, nothing needs L2 residency).
// OOV ids (>= V) land in the pad chunk and get 0 + scatter.

typedef float float4v __attribute__((ext_vector_type(4)));

constexpr int TPB    = 256;
constexpr int CHUNK4 = 2505;                      // float4s per chunk = 40080 B
constexpr int ITERS  = (CHUNK4 + TPB - 1) / TPB;  // 10

__global__ __launch_bounds__(TPB) void pgn_fused_lds_kernel(
    const float* __restrict__ vocab,   // [BT, V]
    const float* __restrict__ attn,    // [BT, L]
    const float* __restrict__ pg,      // [BT]
    const int* __restrict__ ids,       // [B, L]
    float* __restrict__ out,           // [BT, Vext]
    int T, int L, int V4, int Vext4) {
  __shared__ float4v lds[CHUNK4];      // 40080 B -> 4 blocks/CU

  const int row = blockIdx.x;          // 0..B*T-1
  const int tid = threadIdx.x;
  const float p = pg[row];
  const float q = 1.0f - p;
  const int b = row / T;               // scalar once per block

  // Preload this thread's scatter entries (L=400 -> at most 2 per thread).
  const float* __restrict__ arow = attn + (long)row * L;
  const int* __restrict__ irow = ids + (long)b * L;
  int id0 = -1, id1 = -1;
  float s0 = 0.f, s1 = 0.f;
  if (tid < L)       { id0 = irow[tid];       s0 = q * arow[tid]; }
  if (tid + TPB < L) { id1 = irow[tid + TPB]; s1 = q * arow[tid + TPB]; }

  const float4v* __restrict__ vrow =
      reinterpret_cast<const float4v*>(vocab) + (long)row * V4;
  float4v* __restrict__ orow =
      reinterpret_cast<float4v*>(out) + (long)row * Vext4;
  float* ldsf = reinterpret_cast<float*>(lds);

  for (int lo4 = 0; lo4 < Vext4; lo4 += CHUNK4) {
    const int hi4 = min(lo4 + CHUNK4, Vext4);
    const int lof = lo4 * 4, hif = hi4 * 4;

    // Zero the LDS chunk.
    #pragma unroll
    for (int i = 0; i < ITERS; ++i) {
      const int c = tid + i * TPB;
      if (c < CHUNK4) lds[c] = (float4v)(0.f);
    }
    __syncthreads();

    // Scatter this chunk's hits (LDS atomics; ~80 of 400 per chunk).
    if (id0 >= lof && id0 < hif) atomicAdd(ldsf + (id0 - lof), s0);
    if (id1 >= lof && id1 < hif) atomicAdd(ldsf + (id1 - lof), s1);
    __syncthreads();

    // Stream: out = p*vocab + lds (vocab only below V4; pad gets lds only).
    #pragma unroll
    for (int i = 0; i < ITERS; ++i) {
      const int c4 = lo4 + tid + i * TPB;
      if (c4 < hi4) {
        float4v o = lds[c4 - lo4];
        if (c4 < V4) o += p * __builtin_nontemporal_load(vrow + c4);
        __builtin_nontemporal_store(o, orow + c4);
      }
    }
    __syncthreads();  // before reusing LDS for next chunk
  }
}

extern "C" void kernel_launch(void* const* d_in, const int* in_sizes, int n_in,
                              void* d_out, int out_size, void* d_ws, size_t ws_size,
                              hipStream_t stream) {
  const float* vocab = (const float*)d_in[0];   // [B,T,V]
  const float* attn  = (const float*)d_in[1];   // [B,T,L]
  const float* pg    = (const float*)d_in[2];   // [B,T,1]
  const int*   ids   = (const int*)d_in[3];     // [B,L]
  float* out = (float*)d_out;

  const int BT   = in_sizes[2];            // B*T = 1024
  const int V    = in_sizes[0] / BT;       // 50000
  const int L    = in_sizes[1] / BT;       // 400
  const int Vext = out_size / BT;          // 50100
  const int B    = in_sizes[3] / L;        // 16
  const int T    = BT / B;                 // 64

  const int V4 = V / 4, Vext4 = Vext / 4;  // 12500, 12525 (rows 16B-aligned)

  pgn_fused_lds_kernel<<<BT, TPB, 0, stream>>>(vocab, attn, pg, ids, out,
                                               T, L, V4, Vext4);
}